// Round 1
// baseline (1109.408 us; speedup 1.0000x reference)
//
#include <hip/hip_runtime.h>
#include <hip/hip_bf16.h>
#include <cstdint>
#include <cstddef>

#define BN_EPS 1e-5f
typedef long long ll;

// ---------------------------------------------------------------------------
// edge_index dtype detection: if data is int64 (little-endian, values < 2^31),
// every odd dword is a zero high-word. If int32, odd dwords are random node
// ids (~never all zero across 2048 samples). flag = 1 -> int64, 0 -> int32.
__global__ __launch_bounds__(1024) void detect_kernel(const int* ei32, int* flag) {
    __shared__ int any;
    if (threadIdx.x == 0) any = 0;
    __syncthreads();
    for (int i = threadIdx.x; i < 2048; i += 1024) {
        if (ei32[2 * i + 1] != 0) any = 1;
    }
    __syncthreads();
    if (threadIdx.x == 0) *flag = (any == 0) ? 1 : 0;
}

__global__ void init_kernel(int* deg, int* cursor, int N) {
    int i = blockIdx.x * 256 + threadIdx.x;
    if (i < N) { deg[i] = 1; cursor[i] = 0; }  // deg starts at 1 (self loop)
}

__global__ void count_kernel(const void* ei, int E, int* deg, const int* flag) {
    int e = blockIdx.x * 256 + threadIdx.x;
    if (e >= E) return;
    int d = (*flag) ? (int)((const ll*)ei)[(size_t)E + e]
                    : ((const int*)ei)[(size_t)E + e];
    atomicAdd(&deg[d], 1);
}

__global__ void dis_kernel(const int* deg, float* dis, int N) {
    int i = blockIdx.x * 256 + threadIdx.x;
    if (i < N) dis[i] = rsqrtf((float)deg[i]);
}

// Block-level inclusive scan of (deg[i]-1); bsum[b] = block total.
__global__ __launch_bounds__(1024) void scanA_kernel(const int* deg, int* row_ptr,
                                                     int* bsum, int N) {
    __shared__ int wsum[16];
    int i = blockIdx.x * 1024 + threadIdx.x;
    int lane = threadIdx.x & 63, wid = threadIdx.x >> 6;
    int v = (i < N) ? (deg[i] - 1) : 0;
    int s = v;
#pragma unroll
    for (int o = 1; o < 64; o <<= 1) { int t = __shfl_up(s, o); if (lane >= o) s += t; }
    if (lane == 63) wsum[wid] = s;
    __syncthreads();
    if (threadIdx.x < 16) {
        int w = wsum[threadIdx.x];
        int ws_ = w;
#pragma unroll
        for (int o = 1; o < 16; o <<= 1) { int t = __shfl_up(ws_, o); if ((int)threadIdx.x >= o) ws_ += t; }
        wsum[threadIdx.x] = ws_ - w;  // exclusive wave offset
    }
    __syncthreads();
    s += wsum[wid];
    if (i < N) row_ptr[i + 1] = s;
    if (threadIdx.x == 1023) bsum[blockIdx.x] = s;
}

__global__ void scanB_kernel(int* bsum, int nb) {
    int lane = threadIdx.x;
    int v = (lane < nb) ? bsum[lane] : 0;
    int s = v;
#pragma unroll
    for (int o = 1; o < 64; o <<= 1) { int t = __shfl_up(s, o); if (lane >= o) s += t; }
    if (lane < nb) bsum[lane] = s - v;  // exclusive block offsets
}

__global__ __launch_bounds__(1024) void scanC_kernel(int* row_ptr, const int* bsum, int N) {
    int i = blockIdx.x * 1024 + threadIdx.x;
    if (i < N) row_ptr[i + 1] += bsum[blockIdx.x];
    if (i == 0) row_ptr[0] = 0;
}

__global__ void fill_kernel(const void* ei, int E, const int* row_ptr,
                            int* cursor, int* csr, const int* flag) {
    int e = blockIdx.x * 256 + threadIdx.x;
    if (e >= E) return;
    int s, d;
    if (*flag) { const ll* p = (const ll*)ei; s = (int)p[e]; d = (int)p[(size_t)E + e]; }
    else       { const int* p = (const int*)ei; s = p[e]; d = p[(size_t)E + e]; }
    int pos = atomicAdd(&cursor[d], 1);
    csr[row_ptr[d] + pos] = s;
}

// ---------------------------------------------------------------------------
// BN folding: Wp[k][o] = W[k][o] * s[k] (zero-padded to 128 cols),
//             cvec[o]  = sum_k (beta[k]-m[k]*s[k]) * W[k][o]
__global__ void fold_w_kernel(const float* __restrict__ W, const float* __restrict__ g,
                              const float* __restrict__ v, float* __restrict__ Wp,
                              int K, int Dout) {
    int idx = blockIdx.x * 256 + threadIdx.x;
    if (idx >= K * 128) return;
    int k = idx >> 7, o = idx & 127;
    float val = 0.f;
    if (o < Dout) {
        float s = g[k] * rsqrtf(v[k] + BN_EPS);
        val = W[k * Dout + o] * s;
    }
    Wp[idx] = val;
}

__global__ void fold_c_kernel(const float* __restrict__ W, const float* __restrict__ g,
                              const float* __restrict__ bta, const float* __restrict__ m,
                              const float* __restrict__ v, float* __restrict__ cvec,
                              int K, int Dout) {
    int o = threadIdx.x;  // 128 threads
    float acc = 0.f;
    if (o < Dout) {
        for (int k = 0; k < K; ++k) {
            float s = g[k] * rsqrtf(v[k] + BN_EPS);
            acc += (bta[k] - m[k] * s) * W[k * Dout + o];
        }
    }
    cvec[o] = acc;
}

// ---------------------------------------------------------------------------
// GEMM: out[i][o] = dis[i] * ( sum_k X[i][k]*Wp[k][o] + cvec[o] )
// X is the (virtual) concat of X1 [N x K1, ld1] and X2 [N x K2, ld2].
// Tile: 64 rows x 128 cols, BK=64, 256 threads, thread tile 4x8.
__global__ __launch_bounds__(256) void gemm_kernel(
    const float* __restrict__ X1, int K1, int ld1,
    const float* __restrict__ X2, int K2, int ld2,
    const float* __restrict__ Wp, const float* __restrict__ cvec,
    const float* __restrict__ dis,
    float* __restrict__ outp, int ldC, int Dout, int N)
{
    __shared__ float Xs[64 * 64];    // [k][row] with XOR swizzle on row
    __shared__ float Ws[64 * 128];   // [k][col]
    const int tid = threadIdx.x;
    const int tx = tid & 15, ty = tid >> 4;
    const int brow = blockIdx.x * 64;
    const int K = K1 + K2;

    float acc[4][8];
#pragma unroll
    for (int r = 0; r < 4; ++r)
#pragma unroll
        for (int c = 0; c < 4; ++c) {
            acc[r][c]     = cvec[tx * 4 + c];
            acc[r][c + 4] = cvec[64 + tx * 4 + c];
        }

    for (int k0 = 0; k0 < K; k0 += 64) {
        // ---- X tile: rows brow..brow+63, k = k0..k0+63, stored transposed+swizzled
#pragma unroll
        for (int it = 0; it < 4; ++it) {
            int r = ty + 16 * it;          // 0..63
            int grow = brow + r;
            int kq = tx * 4;
            float vx[4];
#pragma unroll
            for (int j = 0; j < 4; ++j) {
                int kk = k0 + kq + j;
                float val = 0.f;
                if (grow < N) {
                    if (kk < K1)      val = X1[(size_t)grow * ld1 + kk];
                    else if (kk < K)  val = X2[(size_t)grow * ld2 + (kk - K1)];
                }
                vx[j] = val;
            }
#pragma unroll
            for (int j = 0; j < 4; ++j) {
                int k = kq + j;
                Xs[k * 64 + (r ^ (((k >> 2) & 7) << 2))] = vx[j];
            }
        }
        // ---- W tile: 64 x 128
#pragma unroll
        for (int it = 0; it < 8; ++it) {
            int kr = (tid >> 5) + 8 * it;
            int col = (tid & 31) * 4;
            int gk = k0 + kr;
            float4 wv = make_float4(0.f, 0.f, 0.f, 0.f);
            if (gk < K) wv = *(const float4*)(Wp + (size_t)gk * 128 + col);
            *(float4*)(Ws + kr * 128 + col) = wv;
        }
        __syncthreads();

#pragma unroll 16
        for (int kk = 0; kk < 64; ++kk) {
            int sw = ((kk >> 2) & 7) << 2;
            float xv[4];
#pragma unroll
            for (int r = 0; r < 4; ++r) xv[r] = Xs[kk * 64 + ((ty * 4 + r) ^ sw)];
            float4 w0 = *(const float4*)(Ws + kk * 128 + tx * 4);
            float4 w1 = *(const float4*)(Ws + kk * 128 + 64 + tx * 4);
#pragma unroll
            for (int r = 0; r < 4; ++r) {
                acc[r][0] += xv[r] * w0.x; acc[r][1] += xv[r] * w0.y;
                acc[r][2] += xv[r] * w0.z; acc[r][3] += xv[r] * w0.w;
                acc[r][4] += xv[r] * w1.x; acc[r][5] += xv[r] * w1.y;
                acc[r][6] += xv[r] * w1.z; acc[r][7] += xv[r] * w1.w;
            }
        }
        __syncthreads();
    }

#pragma unroll
    for (int r = 0; r < 4; ++r) {
        int grow = brow + ty * 4 + r;
        if (grow >= N) continue;
        float d = dis[grow];
        int c0 = tx * 4;
        if (c0 < Dout) {
            float4 o4 = make_float4(d * acc[r][0], d * acc[r][1], d * acc[r][2], d * acc[r][3]);
            *(float4*)(outp + (size_t)grow * ldC + c0) = o4;
        }
        int c1 = 64 + tx * 4;
        if (c1 < Dout) {
            float4 o4 = make_float4(d * acc[r][4], d * acc[r][5], d * acc[r][6], d * acc[r][7]);
            *(float4*)(outp + (size_t)grow * ldC + c1) = o4;
        }
    }
}

// ---------------------------------------------------------------------------
// Aggregation: out[i] = relu?( dis[i]*(sum_{j in CSR(i)} hw[j] + hw[i]) + bias )
// One wave per node; DOUT=128: lane holds 2 floats; DOUT=40: lanes 0..39, 1 float.
template <int DOUT, bool RELU>
__global__ __launch_bounds__(256) void agg_kernel(
    const float* __restrict__ hw, int ldH,
    const int* __restrict__ row_ptr, const int* __restrict__ csr,
    const float* __restrict__ dis, const float* __restrict__ bias,
    float* __restrict__ outp, int N)
{
    int wid = threadIdx.x >> 6, lane = threadIdx.x & 63;
    int node = blockIdx.x * 4 + wid;
    if (node >= N) return;
    int beg = row_ptr[node], end = row_ptr[node + 1];
    float a0 = 0.f, a1 = 0.f, c0 = 0.f, c1 = 0.f;
    if (DOUT == 128) {
        float2 sv = *(const float2*)(hw + (size_t)node * ldH + lane * 2);
        a0 = sv.x; a1 = sv.y;                     // self loop
    } else {
        if (lane < DOUT) a0 = hw[(size_t)node * ldH + lane];
    }
    for (int base = beg; base < end; base += 64) {
        int idx = base + lane;
        int j = (idx < end) ? csr[idx] : 0;
        int cnt = end - base; if (cnt > 64) cnt = 64;
        int t = 0;
        for (; t + 1 < cnt; t += 2) {           // 2-deep for load ILP
            int j0 = __shfl(j, t), j1 = __shfl(j, t + 1);
            if (DOUT == 128) {
                float2 v0 = *(const float2*)(hw + (size_t)j0 * ldH + lane * 2);
                float2 v1 = *(const float2*)(hw + (size_t)j1 * ldH + lane * 2);
                a0 += v0.x; a1 += v0.y; c0 += v1.x; c1 += v1.y;
            } else {
                float v0 = 0.f, v1 = 0.f;
                if (lane < DOUT) { v0 = hw[(size_t)j0 * ldH + lane]; v1 = hw[(size_t)j1 * ldH + lane]; }
                a0 += v0; c0 += v1;
            }
        }
        if (t < cnt) {
            int j0 = __shfl(j, t);
            if (DOUT == 128) {
                float2 v0 = *(const float2*)(hw + (size_t)j0 * ldH + lane * 2);
                a0 += v0.x; a1 += v0.y;
            } else if (lane < DOUT) a0 += hw[(size_t)j0 * ldH + lane];
        }
    }
    a0 += c0; a1 += c1;
    float d = dis[node];
    if (DOUT == 128) {
        float r0 = fmaf(d, a0, bias[lane * 2]);
        float r1 = fmaf(d, a1, bias[lane * 2 + 1]);
        if (RELU) { r0 = fmaxf(r0, 0.f); r1 = fmaxf(r1, 0.f); }
        *(float2*)(outp + (size_t)node * DOUT + lane * 2) = make_float2(r0, r1);
    } else if (lane < DOUT) {
        float r = fmaf(d, a0, bias[lane]);
        if (RELU) r = fmaxf(r, 0.f);
        outp[(size_t)node * DOUT + lane] = r;
    }
}

// ---------------------------------------------------------------------------
extern "C" void kernel_launch(void* const* d_in, const int* in_sizes, int n_in,
                              void* d_out, int out_size, void* d_ws, size_t ws_size,
                              hipStream_t stream) {
    const int N = in_sizes[0] / 100;
    const int E = in_sizes[1] / 2;

    const float* x   = (const float*)d_in[0];
    const void*  ei  = d_in[1];
    const float* W1  = (const float*)d_in[4];
    const float* b1  = (const float*)d_in[5];
    const float* W2  = (const float*)d_in[6];
    const float* b2  = (const float*)d_in[7];
    const float* Wm  = (const float*)d_in[8];
    const float* bm  = (const float*)d_in[9];
    const float* Wo  = (const float*)d_in[10];
    const float* bo  = (const float*)d_in[11];
    const float* bn1g = (const float*)d_in[12];
    const float* bn1b = (const float*)d_in[13];
    const float* bn1m = (const float*)d_in[14];
    const float* bn1v = (const float*)d_in[15];
    const float* bn2g = (const float*)d_in[16];
    const float* bn2b = (const float*)d_in[17];
    const float* bn2m = (const float*)d_in[18];
    const float* bn2v = (const float*)d_in[19];
    const float* bnmg = (const float*)d_in[20];
    const float* bnmb = (const float*)d_in[21];
    const float* bnmm = (const float*)d_in[22];
    const float* bnmv = (const float*)d_in[23];
    const float* bnog = (const float*)d_in[24];
    const float* bnob = (const float*)d_in[25];
    const float* bnom = (const float*)d_in[26];
    const float* bnov = (const float*)d_in[27];

    char* wsb = (char*)d_ws;
    size_t off = 0;
    auto alloc = [&](size_t elems) -> void* { void* p = wsb + off; off += elems * 4; return p; };
    int*   deg     = (int*)alloc(N);
    int*   cursor  = (int*)alloc(N);
    int*   row_ptr = (int*)alloc((size_t)N + 1);
    int*   bsum    = (int*)alloc(64);
    int*   flag    = (int*)alloc(1);
    off = (off + 15) & ~(size_t)15;
    float* dis  = (float*)alloc(N);
    int*   csr  = (int*)alloc(E);
    off = (off + 15) & ~(size_t)15;
    float* hw   = (float*)alloc((size_t)N * 128);
    float* Wp   = (float*)alloc(256 * 128);
    float* cvec = (float*)alloc(128);
    (void)ws_size; (void)n_in; (void)out_size;

    float* outF = (float*)d_out;
    float* h1 = outF + (size_t)N * 40;
    float* h2 = h1 + (size_t)N * 128;
    float* h3 = h2 + (size_t)N * 128;
    float* h4 = h3 + (size_t)N * 128;

    dim3 b256(256);
    detect_kernel<<<1, 1024, 0, stream>>>((const int*)ei, flag);
    init_kernel<<<dim3((N + 255) / 256), b256, 0, stream>>>(deg, cursor, N);
    count_kernel<<<dim3((E + 255) / 256), b256, 0, stream>>>(ei, E, deg, flag);
    dis_kernel<<<dim3((N + 255) / 256), b256, 0, stream>>>(deg, dis, N);
    int nb = (N + 1023) / 1024;
    scanA_kernel<<<dim3(nb), dim3(1024), 0, stream>>>(deg, row_ptr, bsum, N);
    scanB_kernel<<<1, 64, 0, stream>>>(bsum, nb);
    scanC_kernel<<<dim3(nb), dim3(1024), 0, stream>>>(row_ptr, bsum, N);
    fill_kernel<<<dim3((E + 255) / 256), b256, 0, stream>>>(ei, E, row_ptr, cursor, csr, flag);

    int gemm_grid = (N + 63) / 64;
    int agg_grid  = (N + 3) / 4;

    auto layer = [&](const float* X1, int K1, int ld1, const float* X2, int K2, int ld2,
                     const float* W, const float* g, const float* bta, const float* m,
                     const float* v, const float* lb, int Dout, int ldC,
                     float* dst, bool relu) {
        int K = K1 + K2;
        fold_w_kernel<<<dim3((K * 128 + 255) / 256), b256, 0, stream>>>(W, g, v, Wp, K, Dout);
        fold_c_kernel<<<1, 128, 0, stream>>>(W, g, bta, m, v, cvec, K, Dout);
        gemm_kernel<<<dim3(gemm_grid), b256, 0, stream>>>(X1, K1, ld1, X2, K2, ld2,
                                                          Wp, cvec, dis, hw, ldC, Dout, N);
        if (Dout == 128) {
            if (relu)
                agg_kernel<128, true><<<dim3(agg_grid), b256, 0, stream>>>(hw, ldC, row_ptr, csr, dis, lb, dst, N);
            else
                agg_kernel<128, false><<<dim3(agg_grid), b256, 0, stream>>>(hw, ldC, row_ptr, csr, dis, lb, dst, N);
        } else {
            agg_kernel<40, false><<<dim3(agg_grid), b256, 0, stream>>>(hw, ldC, row_ptr, csr, dis, lb, dst, N);
        }
    };

    // L1: bn1 + GCN(W1) + relu -> h1
    layer(x, 100, 100, nullptr, 0, 0, W1, bn1g, bn1b, bn1m, bn1v, b1, 128, 128, h1, true);
    // L2: concat(h1, x) -> bn2 + GCN(W2) + relu -> h2
    layer(h1, 128, 128, x, 100, 100, W2, bn2g, bn2b, bn2m, bn2v, b2, 128, 128, h2, true);
    // L3: concat(h2, h1) -> bnm[0] + GCN(Wm[0]) + relu -> h3
    layer(h2, 128, 128, h1, 128, 128, Wm, bnmg, bnmb, bnmm, bnmv, bm, 128, 128, h3, true);
    // L4: concat(h3, h2) -> bnm[1] + GCN(Wm[1]) + relu -> h4
    layer(h3, 128, 128, h2, 128, 128, Wm + 256 * 128, bnmg + 256, bnmb + 256, bnmm + 256,
          bnmv + 256, bm + 128, 128, 128, h4, true);
    // L5: concat(h4, h3) -> bno + GCN(Wo) -> out (no relu)
    layer(h4, 128, 128, h3, 128, 128, Wo, bnog, bnob, bnom, bnov, bo, 40, 40, outF, false);
}

// Round 2
// 816.014 us; speedup vs baseline: 1.3595x; 1.3595x over previous
//
#include <hip/hip_runtime.h>
#include <hip/hip_bf16.h>
#include <cstdint>
#include <cstddef>

#define BN_EPS 1e-5f
typedef long long ll;
using bf16x8 = __attribute__((ext_vector_type(8))) short;
using f32x4  = __attribute__((ext_vector_type(4))) float;

__device__ __forceinline__ unsigned short f2bf(float f) {
    union { float f; unsigned u; } c; c.f = f;
    unsigned u = c.u;
    u += 0x7fff + ((u >> 16) & 1);   // round-to-nearest-even
    return (unsigned short)(u >> 16);
}
__device__ __forceinline__ float bf2f(unsigned short h) {
    union { unsigned u; float f; } c; c.u = ((unsigned)h) << 16;
    return c.f;
}

// ---------------------------------------------------------------------------
// edge_index dtype detection: int64 (values < 2^31) -> odd dwords all zero.
__global__ __launch_bounds__(1024) void detect_kernel(const int* ei32, int* flag) {
    __shared__ int any;
    if (threadIdx.x == 0) any = 0;
    __syncthreads();
    for (int i = threadIdx.x; i < 2048; i += 1024) {
        if (ei32[2 * i + 1] != 0) any = 1;
    }
    __syncthreads();
    if (threadIdx.x == 0) *flag = (any == 0) ? 1 : 0;
}

__global__ void init_kernel(int* deg, int* cursor, int N) {
    int i = blockIdx.x * 256 + threadIdx.x;
    if (i < N) { deg[i] = 1; cursor[i] = 0; }  // deg starts at 1 (self loop)
}

__global__ void count_kernel(const void* ei, int E, int* deg, const int* flag) {
    int e = blockIdx.x * 256 + threadIdx.x;
    if (e >= E) return;
    int d = (*flag) ? (int)((const ll*)ei)[(size_t)E + e]
                    : ((const int*)ei)[(size_t)E + e];
    atomicAdd(&deg[d], 1);
}

__global__ void dis_kernel(const int* deg, float* dis, int N) {
    int i = blockIdx.x * 256 + threadIdx.x;
    if (i < N) dis[i] = rsqrtf((float)deg[i]);
}

// Block-level inclusive scan of (deg[i]-1); bsum[b] = block total.
__global__ __launch_bounds__(1024) void scanA_kernel(const int* deg, int* row_ptr,
                                                     int* bsum, int N) {
    __shared__ int wsum[16];
    int i = blockIdx.x * 1024 + threadIdx.x;
    int lane = threadIdx.x & 63, wid = threadIdx.x >> 6;
    int v = (i < N) ? (deg[i] - 1) : 0;
    int s = v;
#pragma unroll
    for (int o = 1; o < 64; o <<= 1) { int t = __shfl_up(s, o); if (lane >= o) s += t; }
    if (lane == 63) wsum[wid] = s;
    __syncthreads();
    if (threadIdx.x < 16) {
        int w = wsum[threadIdx.x];
        int ws_ = w;
#pragma unroll
        for (int o = 1; o < 16; o <<= 1) { int t = __shfl_up(ws_, o); if ((int)threadIdx.x >= o) ws_ += t; }
        wsum[threadIdx.x] = ws_ - w;  // exclusive wave offset
    }
    __syncthreads();
    s += wsum[wid];
    if (i < N) row_ptr[i + 1] = s;
    if (threadIdx.x == 1023) bsum[blockIdx.x] = s;
}

__global__ void scanB_kernel(int* bsum, int nb) {
    int lane = threadIdx.x;
    int v = (lane < nb) ? bsum[lane] : 0;
    int s = v;
#pragma unroll
    for (int o = 1; o < 64; o <<= 1) { int t = __shfl_up(s, o); if (lane >= o) s += t; }
    if (lane < nb) bsum[lane] = s - v;  // exclusive block offsets
}

__global__ __launch_bounds__(1024) void scanC_kernel(int* row_ptr, const int* bsum, int N) {
    int i = blockIdx.x * 1024 + threadIdx.x;
    if (i < N) row_ptr[i + 1] += bsum[blockIdx.x];
    if (i == 0) row_ptr[0] = 0;
}

__global__ void fill_kernel(const void* ei, int E, const int* row_ptr,
                            int* cursor, int* csr, const int* flag) {
    int e = blockIdx.x * 256 + threadIdx.x;
    if (e >= E) return;
    int s, d;
    if (*flag) { const ll* p = (const ll*)ei; s = (int)p[e]; d = (int)p[(size_t)E + e]; }
    else       { const int* p = (const int*)ei; s = p[e]; d = p[(size_t)E + e]; }
    int pos = atomicAdd(&cursor[d], 1);
    csr[row_ptr[d] + pos] = s;
}

// ---------------------------------------------------------------------------
// BN fold + MFMA-fragment B packing, split into bf16 hi/lo pair.
// Fragment layout (MUST match A-side loading): lane l, slot i (0..7) holds
// W'[k = kc*32 + 8*(l>>4) + i][col = cb*16 + (l&15)], zero-padded.
__global__ void fold_b_kernel(const float* __restrict__ W, const float* __restrict__ g,
                              const float* __restrict__ v, unsigned short* __restrict__ Bhi,
                              unsigned short* __restrict__ Blo, int K, int Dout, int ncb) {
    int nkc = (K + 31) >> 5;
    int total = nkc * ncb * 512;
    int idx = blockIdx.x * 256 + threadIdx.x;
    if (idx >= total) return;
    int i = idx & 7;
    int lane = (idx >> 3) & 63;
    int cb = (idx >> 9) % ncb;
    int kc = (idx >> 9) / ncb;
    int k = kc * 32 + (lane >> 4) * 8 + i;
    int col = cb * 16 + (lane & 15);
    float val = 0.f;
    if (k < K && col < Dout) {
        float s = g[k] * rsqrtf(v[k] + BN_EPS);
        val = W[k * Dout + col] * s;
    }
    unsigned short h = f2bf(val);
    Bhi[idx] = h;
    Blo[idx] = f2bf(val - bf2f(h));
}

__global__ void fold_c_kernel(const float* __restrict__ W, const float* __restrict__ g,
                              const float* __restrict__ bta, const float* __restrict__ m,
                              const float* __restrict__ v, float* __restrict__ cvec,
                              int K, int Dout) {
    int o = threadIdx.x;  // 128 threads
    float acc = 0.f;
    if (o < Dout) {
        for (int k = 0; k < K; ++k) {
            float s = g[k] * rsqrtf(v[k] + BN_EPS);
            acc += (bta[k] - m[k] * s) * W[k * Dout + o];
        }
    }
    cvec[o] = acc;
}

// ---------------------------------------------------------------------------
// Split-bf16 MFMA GEMM: out[i][o] = dis[i] * (sum_k X[i][k]*W'[k][o] + cvec[o])
// X = virtual concat of X1 [N x K1] and X2. Block: 128 rows, 4 waves; each
// wave owns 32 rows (2 row-frags) x NCB*16 cols. K chunked by 32.
// Product X*W ~= Xhi*Whi + Xhi*Wlo + Xlo*Whi  (3 MFMAs, fp32 accum).
template <int NCB>
__global__ __launch_bounds__(256) void gemm_mfma_kernel(
    const float* __restrict__ X1, int K1, int ld1,
    const float* __restrict__ X2, int ld2,
    const unsigned short* __restrict__ Bhi, const unsigned short* __restrict__ Blo,
    const float* __restrict__ cvec, const float* __restrict__ dis,
    float* __restrict__ outp, int ldC, int Dout, int K, int N)
{
    __shared__ float Xs[128 * 32];     // [row][k], 128B/row, XOR-swizzled 16B chunks
    const int tid = threadIdx.x;
    const int w = tid >> 6, lane = tid & 63;
    const int lr = lane & 15, lg = lane >> 4;
    const int brow = blockIdx.x * 128;
    const int nkc = (K + 31) >> 5;

    f32x4 acc[2][NCB];
#pragma unroll
    for (int cb = 0; cb < NCB; ++cb) {
        float cv = cvec[cb * 16 + lr];
        f32x4 iv = {cv, cv, cv, cv};
        acc[0][cb] = iv;
        acc[1][cb] = iv;
    }

    for (int kc = 0; kc < nkc; ++kc) {
        const int k0 = kc * 32;
        // ---- stage 128x32 fp32 X tile (all K1/K boundaries are 4-aligned,
        //      so each float4 group lies entirely in X1, X2, or pad).
#pragma unroll
        for (int p = 0; p < 4; ++p) {
            int fidx = (p * 256 + tid) * 4;
            int r = fidx >> 5;
            int c = fidx & 31;
            int grow = brow + r;
            int k = k0 + c;
            float4 val = make_float4(0.f, 0.f, 0.f, 0.f);
            if (grow < N) {
                if (k < K1)      val = *(const float4*)(X1 + (size_t)grow * ld1 + k);
                else if (k < K)  val = *(const float4*)(X2 + (size_t)grow * ld2 + (k - K1));
            }
            *(float4*)((char*)Xs + r * 128 + ((c * 4) ^ ((r & 7) << 4))) = val;
        }
        __syncthreads();

        // ---- A fragments: lane reads 8 consecutive k of its row, split hi/lo
        bf16x8 ahi[2], alo[2];
#pragma unroll
        for (int rb = 0; rb < 2; ++rb) {
            int r = w * 32 + rb * 16 + lr;
            const char* base = (const char*)Xs + r * 128;
            int swz = (r & 7) << 4;
            int cb0 = lg * 32;   // byte offset of this lane's 8 floats
            float4 v0 = *(const float4*)(base + (cb0 ^ swz));
            float4 v1 = *(const float4*)(base + ((cb0 + 16) ^ swz));
            float xv[8] = {v0.x, v0.y, v0.z, v0.w, v1.x, v1.y, v1.z, v1.w};
#pragma unroll
            for (int i = 0; i < 8; ++i) {
                unsigned short h = f2bf(xv[i]);
                ahi[rb][i] = (short)h;
                alo[rb][i] = (short)f2bf(xv[i] - bf2f(h));
            }
        }

        // ---- B fragments from global (L2-resident) + MFMAs
        const bf16x8* bh = (const bf16x8*)Bhi + (size_t)kc * NCB * 64;
        const bf16x8* bl = (const bf16x8*)Blo + (size_t)kc * NCB * 64;
#pragma unroll
        for (int cb = 0; cb < NCB; ++cb) {
            bf16x8 bhf = bh[cb * 64 + lane];
            bf16x8 blf = bl[cb * 64 + lane];
#pragma unroll
            for (int rb = 0; rb < 2; ++rb) {
                acc[rb][cb] = __builtin_amdgcn_mfma_f32_16x16x32_bf16(ahi[rb], bhf, acc[rb][cb], 0, 0, 0);
                acc[rb][cb] = __builtin_amdgcn_mfma_f32_16x16x32_bf16(ahi[rb], blf, acc[rb][cb], 0, 0, 0);
                acc[rb][cb] = __builtin_amdgcn_mfma_f32_16x16x32_bf16(alo[rb], bhf, acc[rb][cb], 0, 0, 0);
            }
        }
        __syncthreads();
    }

    // ---- epilogue: D lane map (verified): row = (lane>>4)*4 + reg, col = lane&15
#pragma unroll
    for (int rb = 0; rb < 2; ++rb) {
#pragma unroll
        for (int r = 0; r < 4; ++r) {
            int grow = brow + w * 32 + rb * 16 + lg * 4 + r;
            if (grow >= N) continue;
            float d = dis[grow];
#pragma unroll
            for (int cb = 0; cb < NCB; ++cb) {
                int col = cb * 16 + lr;
                if (col < Dout) outp[(size_t)grow * ldC + col] = d * acc[rb][cb][r];
            }
        }
    }
}

// ---------------------------------------------------------------------------
// Aggregation: out[i] = relu?( dis[i]*(sum_{j in CSR(i)} hw[j] + hw[i]) + bias )
template <int DOUT, bool RELU>
__global__ __launch_bounds__(256) void agg_kernel(
    const float* __restrict__ hw, int ldH,
    const int* __restrict__ row_ptr, const int* __restrict__ csr,
    const float* __restrict__ dis, const float* __restrict__ bias,
    float* __restrict__ outp, int N)
{
    int wid = threadIdx.x >> 6, lane = threadIdx.x & 63;
    int node = blockIdx.x * 4 + wid;
    if (node >= N) return;
    int beg = row_ptr[node], end = row_ptr[node + 1];
    float a0 = 0.f, a1 = 0.f, c0 = 0.f, c1 = 0.f;
    if (DOUT == 128) {
        float2 sv = *(const float2*)(hw + (size_t)node * ldH + lane * 2);
        a0 = sv.x; a1 = sv.y;                     // self loop
    } else {
        if (lane < DOUT) a0 = hw[(size_t)node * ldH + lane];
    }
    for (int base = beg; base < end; base += 64) {
        int idx = base + lane;
        int j = (idx < end) ? csr[idx] : 0;
        int cnt = end - base; if (cnt > 64) cnt = 64;
        int t = 0;
        for (; t + 1 < cnt; t += 2) {           // 2-deep for load ILP
            int j0 = __shfl(j, t), j1 = __shfl(j, t + 1);
            if (DOUT == 128) {
                float2 v0 = *(const float2*)(hw + (size_t)j0 * ldH + lane * 2);
                float2 v1 = *(const float2*)(hw + (size_t)j1 * ldH + lane * 2);
                a0 += v0.x; a1 += v0.y; c0 += v1.x; c1 += v1.y;
            } else {
                float v0 = 0.f, v1 = 0.f;
                if (lane < DOUT) { v0 = hw[(size_t)j0 * ldH + lane]; v1 = hw[(size_t)j1 * ldH + lane]; }
                a0 += v0; c0 += v1;
            }
        }
        if (t < cnt) {
            int j0 = __shfl(j, t);
            if (DOUT == 128) {
                float2 v0 = *(const float2*)(hw + (size_t)j0 * ldH + lane * 2);
                a0 += v0.x; a1 += v0.y;
            } else if (lane < DOUT) a0 += hw[(size_t)j0 * ldH + lane];
        }
    }
    a0 += c0; a1 += c1;
    float d = dis[node];
    if (DOUT == 128) {
        float r0 = fmaf(d, a0, bias[lane * 2]);
        float r1 = fmaf(d, a1, bias[lane * 2 + 1]);
        if (RELU) { r0 = fmaxf(r0, 0.f); r1 = fmaxf(r1, 0.f); }
        *(float2*)(outp + (size_t)node * DOUT + lane * 2) = make_float2(r0, r1);
    } else if (lane < DOUT) {
        float r = fmaf(d, a0, bias[lane]);
        if (RELU) r = fmaxf(r, 0.f);
        outp[(size_t)node * DOUT + lane] = r;
    }
}

// ---------------------------------------------------------------------------
extern "C" void kernel_launch(void* const* d_in, const int* in_sizes, int n_in,
                              void* d_out, int out_size, void* d_ws, size_t ws_size,
                              hipStream_t stream) {
    const int N = in_sizes[0] / 100;
    const int E = in_sizes[1] / 2;

    const float* x   = (const float*)d_in[0];
    const void*  ei  = d_in[1];
    const float* W1  = (const float*)d_in[4];
    const float* b1  = (const float*)d_in[5];
    const float* W2  = (const float*)d_in[6];
    const float* b2  = (const float*)d_in[7];
    const float* Wm  = (const float*)d_in[8];
    const float* bm  = (const float*)d_in[9];
    const float* Wo  = (const float*)d_in[10];
    const float* bo  = (const float*)d_in[11];
    const float* bn1g = (const float*)d_in[12];
    const float* bn1b = (const float*)d_in[13];
    const float* bn1m = (const float*)d_in[14];
    const float* bn1v = (const float*)d_in[15];
    const float* bn2g = (const float*)d_in[16];
    const float* bn2b = (const float*)d_in[17];
    const float* bn2m = (const float*)d_in[18];
    const float* bn2v = (const float*)d_in[19];
    const float* bnmg = (const float*)d_in[20];
    const float* bnmb = (const float*)d_in[21];
    const float* bnmm = (const float*)d_in[22];
    const float* bnmv = (const float*)d_in[23];
    const float* bnog = (const float*)d_in[24];
    const float* bnob = (const float*)d_in[25];
    const float* bnom = (const float*)d_in[26];
    const float* bnov = (const float*)d_in[27];

    char* wsb = (char*)d_ws;
    size_t off = 0;
    auto alloc = [&](size_t elems) -> void* { void* p = wsb + off; off += elems * 4; return p; };
    int*   deg     = (int*)alloc(N);
    int*   cursor  = (int*)alloc(N);
    int*   row_ptr = (int*)alloc((size_t)N + 1);
    int*   bsum    = (int*)alloc(64);
    int*   flag    = (int*)alloc(1);
    off = (off + 15) & ~(size_t)15;
    float* dis  = (float*)alloc(N);
    int*   csr  = (int*)alloc(E);
    off = (off + 15) & ~(size_t)15;
    float* hw   = (float*)alloc((size_t)N * 128);
    unsigned short* BhiA = (unsigned short*)alloc(16384);  // 32768 bf16
    unsigned short* BloA = (unsigned short*)alloc(16384);
    float* cvec = (float*)alloc(128);
    (void)ws_size; (void)n_in; (void)out_size;

    float* outF = (float*)d_out;
    float* h1 = outF + (size_t)N * 40;
    float* h2 = h1 + (size_t)N * 128;
    float* h3 = h2 + (size_t)N * 128;
    float* h4 = h3 + (size_t)N * 128;

    dim3 b256(256);
    detect_kernel<<<1, 1024, 0, stream>>>((const int*)ei, flag);
    init_kernel<<<dim3((N + 255) / 256), b256, 0, stream>>>(deg, cursor, N);
    count_kernel<<<dim3((E + 255) / 256), b256, 0, stream>>>(ei, E, deg, flag);
    dis_kernel<<<dim3((N + 255) / 256), b256, 0, stream>>>(deg, dis, N);
    int nb = (N + 1023) / 1024;
    scanA_kernel<<<dim3(nb), dim3(1024), 0, stream>>>(deg, row_ptr, bsum, N);
    scanB_kernel<<<1, 64, 0, stream>>>(bsum, nb);
    scanC_kernel<<<dim3(nb), dim3(1024), 0, stream>>>(row_ptr, bsum, N);
    fill_kernel<<<dim3((E + 255) / 256), b256, 0, stream>>>(ei, E, row_ptr, cursor, csr, flag);

    int gemm_grid = (N + 127) / 128;
    int agg_grid  = (N + 3) / 4;

    auto layer = [&](const float* X1, int K1, int ld1, const float* X2, int K2, int ld2,
                     const float* W, const float* g, const float* bta, const float* m,
                     const float* v, const float* lb, int Dout, int ldC,
                     float* dst, bool relu) {
        int K = K1 + K2;
        int ncb = (Dout + 15) / 16;
        int nkc = (K + 31) / 32;
        int ftotal = nkc * ncb * 512;
        fold_b_kernel<<<dim3((ftotal + 255) / 256), b256, 0, stream>>>(W, g, v, BhiA, BloA, K, Dout, ncb);
        fold_c_kernel<<<1, 128, 0, stream>>>(W, g, bta, m, v, cvec, K, Dout);
        if (ncb == 8)
            gemm_mfma_kernel<8><<<dim3(gemm_grid), b256, 0, stream>>>(
                X1, K1, ld1, X2, ld2, BhiA, BloA, cvec, dis, hw, ldC, Dout, K, N);
        else
            gemm_mfma_kernel<3><<<dim3(gemm_grid), b256, 0, stream>>>(
                X1, K1, ld1, X2, ld2, BhiA, BloA, cvec, dis, hw, ldC, Dout, K, N);
        if (Dout == 128) {
            if (relu)
                agg_kernel<128, true><<<dim3(agg_grid), b256, 0, stream>>>(hw, ldC, row_ptr, csr, dis, lb, dst, N);
            else
                agg_kernel<128, false><<<dim3(agg_grid), b256, 0, stream>>>(hw, ldC, row_ptr, csr, dis, lb, dst, N);
        } else {
            agg_kernel<40, false><<<dim3(agg_grid), b256, 0, stream>>>(hw, ldC, row_ptr, csr, dis, lb, dst, N);
        }
    };

    // L1: bn1 + GCN(W1) + relu -> h1
    layer(x, 100, 100, nullptr, 0, 0, W1, bn1g, bn1b, bn1m, bn1v, b1, 128, 128, h1, true);
    // L2: concat(h1, x) -> bn2 + GCN(W2) + relu -> h2
    layer(h1, 128, 128, x, 100, 100, W2, bn2g, bn2b, bn2m, bn2v, b2, 128, 128, h2, true);
    // L3: concat(h2, h1) -> bnm[0] + GCN(Wm[0]) + relu -> h3
    layer(h2, 128, 128, h1, 128, 128, Wm, bnmg, bnmb, bnmm, bnmv, bm, 128, 128, h3, true);
    // L4: concat(h3, h2) -> bnm[1] + GCN(Wm[1]) + relu -> h4
    layer(h3, 128, 128, h2, 128, 128, Wm + 256 * 128, bnmg + 256, bnmb + 256, bnmm + 256,
          bnmv + 256, bm + 128, 128, 128, h4, true);
    // L5: concat(h4, h3) -> bno + GCN(Wo) -> out (no relu)
    layer(h4, 128, 128, h3, 128, 128, Wo, bnog, bnob, bnom, bnov, bo, 40, 40, outF, false);
}

// Round 3
// 577.611 us; speedup vs baseline: 1.9207x; 1.4127x over previous
//
#include <hip/hip_runtime.h>
#include <hip/hip_bf16.h>
#include <cstdint>
#include <cstddef>

#define BN_EPS 1e-5f
typedef long long ll;
using bf16x8 = __attribute__((ext_vector_type(8))) short;
using f32x4  = __attribute__((ext_vector_type(4))) float;

__device__ __forceinline__ unsigned short f2bf(float f) {
    union { float f; unsigned u; } c; c.f = f;
    unsigned u = c.u;
    u += 0x7fff + ((u >> 16) & 1);   // round-to-nearest-even
    return (unsigned short)(u >> 16);
}
__device__ __forceinline__ float bf2f(unsigned short h) {
    union { unsigned u; float f; } c; c.u = ((unsigned)h) << 16;
    return c.f;
}
__device__ __forceinline__ void add4(float4& a, const float4& b) {
    a.x += b.x; a.y += b.y; a.z += b.z; a.w += b.w;
}

// ---------------------------------------------------------------------------
// edge_index dtype detection: int64 (values < 2^31) -> odd dwords all zero.
__global__ __launch_bounds__(1024) void detect_kernel(const int* ei32, int* flag) {
    __shared__ int any;
    if (threadIdx.x == 0) any = 0;
    __syncthreads();
    for (int i = threadIdx.x; i < 2048; i += 1024) {
        if (ei32[2 * i + 1] != 0) any = 1;
    }
    __syncthreads();
    if (threadIdx.x == 0) *flag = (any == 0) ? 1 : 0;
}

__global__ void init_kernel(int* deg, int* cursor, int N) {
    int i = blockIdx.x * 256 + threadIdx.x;
    if (i < N) { deg[i] = 1; cursor[i] = 0; }  // deg starts at 1 (self loop)
}

__global__ void count_kernel(const void* ei, int E, int* deg, const int* flag) {
    int e = blockIdx.x * 256 + threadIdx.x;
    if (e >= E) return;
    int d = (*flag) ? (int)((const ll*)ei)[(size_t)E + e]
                    : ((const int*)ei)[(size_t)E + e];
    atomicAdd(&deg[d], 1);
}

__global__ void dis_kernel(const int* deg, float* dis, int N) {
    int i = blockIdx.x * 256 + threadIdx.x;
    if (i < N) dis[i] = rsqrtf((float)deg[i]);
}

// Block-level inclusive scan of (deg[i]-1); bsum[b] = block total.
__global__ __launch_bounds__(1024) void scanA_kernel(const int* deg, int* row_ptr,
                                                     int* bsum, int N) {
    __shared__ int wsum[16];
    int i = blockIdx.x * 1024 + threadIdx.x;
    int lane = threadIdx.x & 63, wid = threadIdx.x >> 6;
    int v = (i < N) ? (deg[i] - 1) : 0;
    int s = v;
#pragma unroll
    for (int o = 1; o < 64; o <<= 1) { int t = __shfl_up(s, o); if (lane >= o) s += t; }
    if (lane == 63) wsum[wid] = s;
    __syncthreads();
    if (threadIdx.x < 16) {
        int w = wsum[threadIdx.x];
        int ws_ = w;
#pragma unroll
        for (int o = 1; o < 16; o <<= 1) { int t = __shfl_up(ws_, o); if ((int)threadIdx.x >= o) ws_ += t; }
        wsum[threadIdx.x] = ws_ - w;  // exclusive wave offset
    }
    __syncthreads();
    s += wsum[wid];
    if (i < N) row_ptr[i + 1] = s;
    if (threadIdx.x == 1023) bsum[blockIdx.x] = s;
}

__global__ void scanB_kernel(int* bsum, int nb) {
    int lane = threadIdx.x;
    int v = (lane < nb) ? bsum[lane] : 0;
    int s = v;
#pragma unroll
    for (int o = 1; o < 64; o <<= 1) { int t = __shfl_up(s, o); if (lane >= o) s += t; }
    if (lane < nb) bsum[lane] = s - v;  // exclusive block offsets
}

__global__ __launch_bounds__(1024) void scanC_kernel(int* row_ptr, const int* bsum, int N) {
    int i = blockIdx.x * 1024 + threadIdx.x;
    if (i < N) row_ptr[i + 1] += bsum[blockIdx.x];
    if (i == 0) row_ptr[0] = 0;
}

__global__ void fill_kernel(const void* ei, int E, const int* row_ptr,
                            int* cursor, int* csr, const int* flag) {
    int e = blockIdx.x * 256 + threadIdx.x;
    if (e >= E) return;
    int s, d;
    if (*flag) { const ll* p = (const ll*)ei; s = (int)p[e]; d = (int)p[(size_t)E + e]; }
    else       { const int* p = (const int*)ei; s = p[e]; d = p[(size_t)E + e]; }
    int pos = atomicAdd(&cursor[d], 1);
    csr[row_ptr[d] + pos] = s;
}

// ---------------------------------------------------------------------------
// BN fold + MFMA-fragment B packing, split into bf16 hi/lo pair.
// Fragment layout (MUST match A-side loading): lane l, slot i (0..7) holds
// W'[k = kc*32 + 8*(l>>4) + i][col = cb*16 + (l&15)], zero-padded.
__global__ void fold_b_kernel(const float* __restrict__ W, const float* __restrict__ g,
                              const float* __restrict__ v, unsigned short* __restrict__ Bhi,
                              unsigned short* __restrict__ Blo, int K, int Dout, int ncb) {
    int nkc = (K + 31) >> 5;
    int total = nkc * ncb * 512;
    int idx = blockIdx.x * 256 + threadIdx.x;
    if (idx >= total) return;
    int i = idx & 7;
    int lane = (idx >> 3) & 63;
    int cb = (idx >> 9) % ncb;
    int kc = (idx >> 9) / ncb;
    int k = kc * 32 + (lane >> 4) * 8 + i;
    int col = cb * 16 + (lane & 15);
    float val = 0.f;
    if (k < K && col < Dout) {
        float s = g[k] * rsqrtf(v[k] + BN_EPS);
        val = W[k * Dout + col] * s;
    }
    unsigned short h = f2bf(val);
    Bhi[idx] = h;
    Blo[idx] = f2bf(val - bf2f(h));
}

// cvec[col] = sum_k (beta[k]-m[k]*s[k]) * W[k][col]; one wave per col, 128 cols.
__global__ __launch_bounds__(256) void fold_c2_kernel(
    const float* __restrict__ W, const float* __restrict__ g,
    const float* __restrict__ bta, const float* __restrict__ m,
    const float* __restrict__ v, float* __restrict__ cvec, int K, int Dout) {
    int wid = threadIdx.x >> 6, lane = threadIdx.x & 63;
    int col = blockIdx.x * 4 + wid;
    float acc = 0.f;
    if (col < Dout) {
        for (int k = lane; k < K; k += 64) {
            float s = g[k] * rsqrtf(v[k] + BN_EPS);
            acc += (bta[k] - m[k] * s) * W[k * Dout + col];
        }
    }
#pragma unroll
    for (int o = 32; o >= 1; o >>= 1) acc += __shfl_xor(acc, o);
    if (lane == 0 && col < 128) cvec[col] = (col < Dout) ? acc : 0.f;
}

// ---------------------------------------------------------------------------
// Split-bf16 MFMA GEMM: out[i][o] = dis[i] * (sum_k X[i][k]*W'[k][o] + cvec[o])
template <int NCB>
__global__ __launch_bounds__(256) void gemm_mfma_kernel(
    const float* __restrict__ X1, int K1, int ld1,
    const float* __restrict__ X2, int ld2,
    const unsigned short* __restrict__ Bhi, const unsigned short* __restrict__ Blo,
    const float* __restrict__ cvec, const float* __restrict__ dis,
    float* __restrict__ outp, int ldC, int Dout, int K, int N)
{
    __shared__ float Xs[128 * 32];     // [row][k], 128B/row, XOR-swizzled 16B chunks
    const int tid = threadIdx.x;
    const int w = tid >> 6, lane = tid & 63;
    const int lr = lane & 15, lg = lane >> 4;
    const int brow = blockIdx.x * 128;
    const int nkc = (K + 31) >> 5;

    f32x4 acc[2][NCB];
#pragma unroll
    for (int cb = 0; cb < NCB; ++cb) {
        float cv = cvec[cb * 16 + lr];
        f32x4 iv = {cv, cv, cv, cv};
        acc[0][cb] = iv;
        acc[1][cb] = iv;
    }

    for (int kc = 0; kc < nkc; ++kc) {
        const int k0 = kc * 32;
#pragma unroll
        for (int p = 0; p < 4; ++p) {
            int fidx = (p * 256 + tid) * 4;
            int r = fidx >> 5;
            int c = fidx & 31;
            int grow = brow + r;
            int k = k0 + c;
            float4 val = make_float4(0.f, 0.f, 0.f, 0.f);
            if (grow < N) {
                if (k < K1)      val = *(const float4*)(X1 + (size_t)grow * ld1 + k);
                else if (k < K)  val = *(const float4*)(X2 + (size_t)grow * ld2 + (k - K1));
            }
            *(float4*)((char*)Xs + r * 128 + ((c * 4) ^ ((r & 7) << 4))) = val;
        }
        __syncthreads();

        bf16x8 ahi[2], alo[2];
#pragma unroll
        for (int rb = 0; rb < 2; ++rb) {
            int r = w * 32 + rb * 16 + lr;
            const char* base = (const char*)Xs + r * 128;
            int swz = (r & 7) << 4;
            int cb0 = lg * 32;
            float4 v0 = *(const float4*)(base + (cb0 ^ swz));
            float4 v1 = *(const float4*)(base + ((cb0 + 16) ^ swz));
            float xv[8] = {v0.x, v0.y, v0.z, v0.w, v1.x, v1.y, v1.z, v1.w};
#pragma unroll
            for (int i = 0; i < 8; ++i) {
                unsigned short h = f2bf(xv[i]);
                ahi[rb][i] = (short)h;
                alo[rb][i] = (short)f2bf(xv[i] - bf2f(h));
            }
        }

        const bf16x8* bh = (const bf16x8*)Bhi + (size_t)kc * NCB * 64;
        const bf16x8* bl = (const bf16x8*)Blo + (size_t)kc * NCB * 64;
#pragma unroll
        for (int cb = 0; cb < NCB; ++cb) {
            bf16x8 bhf = bh[cb * 64 + lane];
            bf16x8 blf = bl[cb * 64 + lane];
#pragma unroll
            for (int rb = 0; rb < 2; ++rb) {
                acc[rb][cb] = __builtin_amdgcn_mfma_f32_16x16x32_bf16(ahi[rb], bhf, acc[rb][cb], 0, 0, 0);
                acc[rb][cb] = __builtin_amdgcn_mfma_f32_16x16x32_bf16(ahi[rb], blf, acc[rb][cb], 0, 0, 0);
                acc[rb][cb] = __builtin_amdgcn_mfma_f32_16x16x32_bf16(alo[rb], bhf, acc[rb][cb], 0, 0, 0);
            }
        }
        __syncthreads();
    }

#pragma unroll
    for (int rb = 0; rb < 2; ++rb) {
#pragma unroll
        for (int r = 0; r < 4; ++r) {
            int grow = brow + w * 32 + rb * 16 + lg * 4 + r;
            if (grow >= N) continue;
            float d = dis[grow];
#pragma unroll
            for (int cb = 0; cb < NCB; ++cb) {
                int col = cb * 16 + lr;
                if (col < Dout) outp[(size_t)grow * ldC + col] = d * acc[rb][cb][r];
            }
        }
    }
}

// ---------------------------------------------------------------------------
// 128-wide aggregation, dual-row float4 gather:
// lanes 0-31 fetch even neighbors, 32-63 odd; 8 rows (4KB) in flight.
template <bool RELU>
__global__ __launch_bounds__(256) void agg128_kernel(
    const float* __restrict__ hw, int ldH,
    const int* __restrict__ row_ptr, const int* __restrict__ csr,
    const float* __restrict__ dis, const float* __restrict__ bias,
    float* __restrict__ outp, int N)
{
    int wid = threadIdx.x >> 6, lane = threadIdx.x & 63;
    int node = blockIdx.x * 4 + wid;
    if (node >= N) return;
    const int half = lane >> 5, q = lane & 31;
    const int s4 = ldH >> 2;
    const float4* hw4 = (const float4*)hw;
    float4 acc0 = {0,0,0,0}, acc1 = {0,0,0,0}, acc2 = {0,0,0,0}, acc3 = {0,0,0,0};
    if (half == 0) acc0 = hw4[(size_t)node * s4 + q];   // self loop
    int beg = row_ptr[node], end = row_ptr[node + 1];
    for (int base = beg; base < end; base += 64) {
        int idx = base + lane;
        int j = (idx < end) ? csr[idx] : 0;
        int cnt = end - base; if (cnt > 64) cnt = 64;
        int fullp = cnt >> 1;
        int t = 0;
        for (; t + 4 <= fullp; t += 4) {
            int ja = __shfl(j, 2 * t     + half);
            int jb = __shfl(j, 2 * t + 2 + half);
            int jc = __shfl(j, 2 * t + 4 + half);
            int jd = __shfl(j, 2 * t + 6 + half);
            float4 va = hw4[(size_t)ja * s4 + q];
            float4 vb = hw4[(size_t)jb * s4 + q];
            float4 vc = hw4[(size_t)jc * s4 + q];
            float4 vd = hw4[(size_t)jd * s4 + q];
            add4(acc0, va); add4(acc1, vb); add4(acc2, vc); add4(acc3, vd);
        }
        for (; t < fullp; ++t) {
            int ja = __shfl(j, 2 * t + half);
            float4 va = hw4[(size_t)ja * s4 + q];
            add4(acc0, va);
        }
        if (cnt & 1) {
            int ja = __shfl(j, cnt - 1);
            if (half == 0) { float4 va = hw4[(size_t)ja * s4 + q]; add4(acc0, va); }
        }
    }
    float a[4];
    a[0] = acc0.x + acc1.x + acc2.x + acc3.x;
    a[1] = acc0.y + acc1.y + acc2.y + acc3.y;
    a[2] = acc0.z + acc1.z + acc2.z + acc3.z;
    a[3] = acc0.w + acc1.w + acc2.w + acc3.w;
#pragma unroll
    for (int c = 0; c < 4; ++c) a[c] += __shfl_xor(a[c], 32);
    if (half == 0) {
        float d = dis[node];
        float4 bv = ((const float4*)bias)[q];
        float4 o;
        o.x = fmaf(d, a[0], bv.x);
        o.y = fmaf(d, a[1], bv.y);
        o.z = fmaf(d, a[2], bv.z);
        o.w = fmaf(d, a[3], bv.w);
        if (RELU) {
            o.x = fmaxf(o.x, 0.f); o.y = fmaxf(o.y, 0.f);
            o.z = fmaxf(o.z, 0.f); o.w = fmaxf(o.w, 0.f);
        }
        ((float4*)outp)[(size_t)node * 32 + q] = o;
    }
}

// 40-wide aggregation, 4-deep unroll.
__global__ __launch_bounds__(256) void agg40_kernel(
    const float* __restrict__ hw,
    const int* __restrict__ row_ptr, const int* __restrict__ csr,
    const float* __restrict__ dis, const float* __restrict__ bias,
    float* __restrict__ outp, int N)
{
    int wid = threadIdx.x >> 6, lane = threadIdx.x & 63;
    int node = blockIdx.x * 4 + wid;
    if (node >= N) return;
    bool act = lane < 40;
    float a0 = 0.f, a1 = 0.f, a2 = 0.f, a3 = 0.f;
    if (act) a0 = hw[(size_t)node * 40 + lane];
    int beg = row_ptr[node], end = row_ptr[node + 1];
    for (int base = beg; base < end; base += 64) {
        int idx = base + lane;
        int j = (idx < end) ? csr[idx] : 0;
        int cnt = end - base; if (cnt > 64) cnt = 64;
        int t = 0;
        for (; t + 4 <= cnt; t += 4) {
            int j0 = __shfl(j, t), j1 = __shfl(j, t + 1);
            int j2 = __shfl(j, t + 2), j3 = __shfl(j, t + 3);
            if (act) {
                a0 += hw[(size_t)j0 * 40 + lane];
                a1 += hw[(size_t)j1 * 40 + lane];
                a2 += hw[(size_t)j2 * 40 + lane];
                a3 += hw[(size_t)j3 * 40 + lane];
            }
        }
        for (; t < cnt; ++t) {
            int j0 = __shfl(j, t);
            if (act) a0 += hw[(size_t)j0 * 40 + lane];
        }
    }
    if (act) {
        float s = (a0 + a1) + (a2 + a3);
        outp[(size_t)node * 40 + lane] = fmaf(dis[node], s, bias[lane]);
    }
}

// ---------------------------------------------------------------------------
extern "C" void kernel_launch(void* const* d_in, const int* in_sizes, int n_in,
                              void* d_out, int out_size, void* d_ws, size_t ws_size,
                              hipStream_t stream) {
    const int N = in_sizes[0] / 100;
    const int E = in_sizes[1] / 2;

    const float* x   = (const float*)d_in[0];
    const void*  ei  = d_in[1];
    const float* W1  = (const float*)d_in[4];
    const float* b1  = (const float*)d_in[5];
    const float* W2  = (const float*)d_in[6];
    const float* b2  = (const float*)d_in[7];
    const float* Wm  = (const float*)d_in[8];
    const float* bm  = (const float*)d_in[9];
    const float* Wo  = (const float*)d_in[10];
    const float* bo  = (const float*)d_in[11];
    const float* bn1g = (const float*)d_in[12];
    const float* bn1b = (const float*)d_in[13];
    const float* bn1m = (const float*)d_in[14];
    const float* bn1v = (const float*)d_in[15];
    const float* bn2g = (const float*)d_in[16];
    const float* bn2b = (const float*)d_in[17];
    const float* bn2m = (const float*)d_in[18];
    const float* bn2v = (const float*)d_in[19];
    const float* bnmg = (const float*)d_in[20];
    const float* bnmb = (const float*)d_in[21];
    const float* bnmm = (const float*)d_in[22];
    const float* bnmv = (const float*)d_in[23];
    const float* bnog = (const float*)d_in[24];
    const float* bnob = (const float*)d_in[25];
    const float* bnom = (const float*)d_in[26];
    const float* bnov = (const float*)d_in[27];

    char* wsb = (char*)d_ws;
    size_t off = 0;
    auto alloc = [&](size_t elems) -> void* { void* p = wsb + off; off += elems * 4; return p; };
    int*   deg     = (int*)alloc(N);
    int*   cursor  = (int*)alloc(N);
    int*   row_ptr = (int*)alloc((size_t)N + 1);
    int*   bsum    = (int*)alloc(64);
    int*   flag    = (int*)alloc(1);
    off = (off + 15) & ~(size_t)15;
    float* dis  = (float*)alloc(N);
    int*   csr  = (int*)alloc(E);
    off = (off + 15) & ~(size_t)15;
    float* hw   = (float*)alloc((size_t)N * 128);
    unsigned short* BhiA = (unsigned short*)alloc(63488);   // 126976 bf16 arena
    unsigned short* BloA = (unsigned short*)alloc(63488);
    float* cvecA = (float*)alloc(128 * 5);
    (void)ws_size; (void)n_in; (void)out_size;

    float* outF = (float*)d_out;
    float* h1 = outF + (size_t)N * 40;
    float* h2 = h1 + (size_t)N * 128;
    float* h3 = h2 + (size_t)N * 128;
    float* h4 = h3 + (size_t)N * 128;

    dim3 b256(256);

    // ---- fold all 5 layers' weights up front (independent of graph build)
    const int Boff[5]  = {0, 16384, 49152, 81920, 114688};
    struct FoldP { const float *W, *g, *b, *m, *v; int K, Dout, ncb; };
    FoldP fp[5] = {
        {W1, bn1g, bn1b, bn1m, bn1v, 100, 128, 8},
        {W2, bn2g, bn2b, bn2m, bn2v, 228, 128, 8},
        {Wm, bnmg, bnmb, bnmm, bnmv, 256, 128, 8},
        {Wm + 256 * 128, bnmg + 256, bnmb + 256, bnmm + 256, bnmv + 256, 256, 128, 8},
        {Wo, bnog, bnob, bnom, bnov, 256, 40, 3},
    };
    for (int l = 0; l < 5; ++l) {
        int nkc = (fp[l].K + 31) / 32;
        int ftotal = nkc * fp[l].ncb * 512;
        fold_b_kernel<<<dim3((ftotal + 255) / 256), b256, 0, stream>>>(
            fp[l].W, fp[l].g, fp[l].v, BhiA + Boff[l], BloA + Boff[l], fp[l].K, fp[l].Dout, fp[l].ncb);
        fold_c2_kernel<<<dim3(32), b256, 0, stream>>>(
            fp[l].W, fp[l].g, fp[l].b, fp[l].m, fp[l].v, cvecA + 128 * l, fp[l].K, fp[l].Dout);
    }

    // ---- graph build
    detect_kernel<<<1, 1024, 0, stream>>>((const int*)ei, flag);
    init_kernel<<<dim3((N + 255) / 256), b256, 0, stream>>>(deg, cursor, N);
    count_kernel<<<dim3((E + 255) / 256), b256, 0, stream>>>(ei, E, deg, flag);
    dis_kernel<<<dim3((N + 255) / 256), b256, 0, stream>>>(deg, dis, N);
    int nb = (N + 1023) / 1024;
    scanA_kernel<<<dim3(nb), dim3(1024), 0, stream>>>(deg, row_ptr, bsum, N);
    scanB_kernel<<<1, 64, 0, stream>>>(bsum, nb);
    scanC_kernel<<<dim3(nb), dim3(1024), 0, stream>>>(row_ptr, bsum, N);
    fill_kernel<<<dim3((E + 255) / 256), b256, 0, stream>>>(ei, E, row_ptr, cursor, csr, flag);

    int gemm_grid = (N + 127) / 128;
    int agg_grid  = (N + 3) / 4;

    auto layer = [&](int l, const float* X1, int K1, int ld1, const float* X2, int ld2,
                     const float* lb, int Dout, int ldC, float* dst, bool relu) {
        int K = fp[l].K;
        const unsigned short* Bhi = BhiA + Boff[l];
        const unsigned short* Blo = BloA + Boff[l];
        const float* cv = cvecA + 128 * l;
        if (fp[l].ncb == 8)
            gemm_mfma_kernel<8><<<dim3(gemm_grid), b256, 0, stream>>>(
                X1, K1, ld1, X2, ld2, Bhi, Blo, cv, dis, hw, ldC, Dout, K, N);
        else
            gemm_mfma_kernel<3><<<dim3(gemm_grid), b256, 0, stream>>>(
                X1, K1, ld1, X2, ld2, Bhi, Blo, cv, dis, hw, ldC, Dout, K, N);
        if (Dout == 128) {
            if (relu)
                agg128_kernel<true><<<dim3(agg_grid), b256, 0, stream>>>(hw, ldC, row_ptr, csr, dis, lb, dst, N);
            else
                agg128_kernel<false><<<dim3(agg_grid), b256, 0, stream>>>(hw, ldC, row_ptr, csr, dis, lb, dst, N);
        } else {
            agg40_kernel<<<dim3(agg_grid), b256, 0, stream>>>(hw, row_ptr, csr, dis, lb, dst, N);
        }
    };

    // L1: bn1 + GCN(W1) + relu -> h1
    layer(0, x, 100, 100, nullptr, 0, b1, 128, 128, h1, true);
    // L2: concat(h1, x) -> bn2 + GCN(W2) + relu -> h2
    layer(1, h1, 128, 128, x, 100, b2, 128, 128, h2, true);
    // L3: concat(h2, h1) -> bnm[0] + GCN(Wm[0]) + relu -> h3
    layer(2, h2, 128, 128, h1, 128, bm, 128, 128, h3, true);
    // L4: concat(h3, h2) -> bnm[1] + GCN(Wm[1]) + relu -> h4
    layer(3, h3, 128, 128, h2, 128, bm + 128, 128, 128, h4, true);
    // L5: concat(h4, h3) -> bno + GCN(Wo) -> out (no relu)
    layer(4, h4, 128, 128, h3, 128, bo, 40, 40, outF, false);
}

// Round 4
// 442.819 us; speedup vs baseline: 2.5053x; 1.3044x over previous
//
#include <hip/hip_runtime.h>
#include <hip/hip_bf16.h>
#include <cstdint>
#include <cstddef>

#define BN_EPS 1e-5f
typedef long long ll;
typedef unsigned short ushortt;
using bf16x8 = __attribute__((ext_vector_type(8))) short;
using f32x4  = __attribute__((ext_vector_type(4))) float;

__device__ __forceinline__ unsigned short f2bf(float f) {
    union { float f; unsigned u; } c; c.f = f;
    unsigned u = c.u;
    u += 0x7fff + ((u >> 16) & 1);   // round-to-nearest-even
    return (unsigned short)(u >> 16);
}
__device__ __forceinline__ float bf2f(unsigned h) {
    union { unsigned u; float f; } c; c.u = h << 16;
    return c.f;
}
__device__ __forceinline__ void addbf(float* a, uint2 v) {
    a[0] += bf2f(v.x & 0xffffu); a[1] += bf2f(v.x >> 16);
    a[2] += bf2f(v.y & 0xffffu); a[3] += bf2f(v.y >> 16);
}

// ---------------------------------------------------------------------------
// edge_index dtype detection: int64 (values < 2^31) -> odd dwords all zero.
__global__ __launch_bounds__(1024) void detect_kernel(const int* ei32, int* flag) {
    __shared__ int any;
    if (threadIdx.x == 0) any = 0;
    __syncthreads();
    for (int i = threadIdx.x; i < 2048; i += 1024) {
        if (ei32[2 * i + 1] != 0) any = 1;
    }
    __syncthreads();
    if (threadIdx.x == 0) *flag = (any == 0) ? 1 : 0;
}

__global__ void init_kernel(int* deg, int* cursor, int N) {
    int i = blockIdx.x * 256 + threadIdx.x;
    if (i < N) { deg[i] = 1; cursor[i] = 0; }  // deg starts at 1 (self loop)
}

__global__ void count_kernel(const void* ei, int E, int* deg, const int* flag) {
    int e = blockIdx.x * 256 + threadIdx.x;
    if (e >= E) return;
    int d = (*flag) ? (int)((const ll*)ei)[(size_t)E + e]
                    : ((const int*)ei)[(size_t)E + e];
    atomicAdd(&deg[d], 1);
}

__global__ void dis_kernel(const int* deg, float* dis, int N) {
    int i = blockIdx.x * 256 + threadIdx.x;
    if (i < N) dis[i] = rsqrtf((float)deg[i]);
}

// Block-level inclusive scan of (deg[i]-1); bsum[b] = block total.
__global__ __launch_bounds__(1024) void scanA_kernel(const int* deg, int* row_ptr,
                                                     int* bsum, int N) {
    __shared__ int wsum[16];
    int i = blockIdx.x * 1024 + threadIdx.x;
    int lane = threadIdx.x & 63, wid = threadIdx.x >> 6;
    int v = (i < N) ? (deg[i] - 1) : 0;
    int s = v;
#pragma unroll
    for (int o = 1; o < 64; o <<= 1) { int t = __shfl_up(s, o); if (lane >= o) s += t; }
    if (lane == 63) wsum[wid] = s;
    __syncthreads();
    if (threadIdx.x < 16) {
        int w = wsum[threadIdx.x];
        int ws_ = w;
#pragma unroll
        for (int o = 1; o < 16; o <<= 1) { int t = __shfl_up(ws_, o); if ((int)threadIdx.x >= o) ws_ += t; }
        wsum[threadIdx.x] = ws_ - w;  // exclusive wave offset
    }
    __syncthreads();
    s += wsum[wid];
    if (i < N) row_ptr[i + 1] = s;
    if (threadIdx.x == 1023) bsum[blockIdx.x] = s;
}

__global__ void scanB_kernel(int* bsum, int nb) {
    int lane = threadIdx.x;
    int v = (lane < nb) ? bsum[lane] : 0;
    int s = v;
#pragma unroll
    for (int o = 1; o < 64; o <<= 1) { int t = __shfl_up(s, o); if (lane >= o) s += t; }
    if (lane < nb) bsum[lane] = s - v;  // exclusive block offsets
}

__global__ __launch_bounds__(1024) void scanC_kernel(int* row_ptr, const int* bsum, int N) {
    int i = blockIdx.x * 1024 + threadIdx.x;
    if (i < N) row_ptr[i + 1] += bsum[blockIdx.x];
    if (i == 0) row_ptr[0] = 0;
}

__global__ void fill_kernel(const void* ei, int E, const int* row_ptr,
                            int* cursor, int* csr, const int* flag) {
    int e = blockIdx.x * 256 + threadIdx.x;
    if (e >= E) return;
    int s, d;
    if (*flag) { const ll* p = (const ll*)ei; s = (int)p[e]; d = (int)p[(size_t)E + e]; }
    else       { const int* p = (const int*)ei; s = p[e]; d = p[(size_t)E + e]; }
    int pos = atomicAdd(&cursor[d], 1);
    csr[row_ptr[d] + pos] = s;
}

// ---------------------------------------------------------------------------
// BN fold + MFMA-fragment B packing, split into bf16 hi/lo pair.
__global__ void fold_b_kernel(const float* __restrict__ W, const float* __restrict__ g,
                              const float* __restrict__ v, unsigned short* __restrict__ Bhi,
                              unsigned short* __restrict__ Blo, int K, int Dout, int ncb) {
    int nkc = (K + 31) >> 5;
    int total = nkc * ncb * 512;
    int idx = blockIdx.x * 256 + threadIdx.x;
    if (idx >= total) return;
    int i = idx & 7;
    int lane = (idx >> 3) & 63;
    int cb = (idx >> 9) % ncb;
    int kc = (idx >> 9) / ncb;
    int k = kc * 32 + (lane >> 4) * 8 + i;
    int col = cb * 16 + (lane & 15);
    float val = 0.f;
    if (k < K && col < Dout) {
        float s = g[k] * rsqrtf(v[k] + BN_EPS);
        val = W[k * Dout + col] * s;
    }
    unsigned short h = f2bf(val);
    Bhi[idx] = h;
    Blo[idx] = f2bf(val - bf2f(h));
}

// cvec[col] = sum_k (beta[k]-m[k]*s[k]) * W[k][col]; one wave per col.
__global__ __launch_bounds__(256) void fold_c2_kernel(
    const float* __restrict__ W, const float* __restrict__ g,
    const float* __restrict__ bta, const float* __restrict__ m,
    const float* __restrict__ v, float* __restrict__ cvec, int K, int Dout) {
    int wid = threadIdx.x >> 6, lane = threadIdx.x & 63;
    int col = blockIdx.x * 4 + wid;
    float acc = 0.f;
    if (col < Dout) {
        for (int k = lane; k < K; k += 64) {
            float s = g[k] * rsqrtf(v[k] + BN_EPS);
            acc += (bta[k] - m[k] * s) * W[k * Dout + col];
        }
    }
#pragma unroll
    for (int o = 32; o >= 1; o >>= 1) acc += __shfl_xor(acc, o);
    if (lane == 0 && col < 128) cvec[col] = (col < Dout) ? acc : 0.f;
}

// ---------------------------------------------------------------------------
// Split-bf16 MFMA GEMM. BF16OUT: write N x 128 bf16 (for gather layers);
// else fp32 N x ldC.
template <int NCB, bool BF16OUT>
__global__ __launch_bounds__(256) void gemm_mfma_kernel(
    const float* __restrict__ X1, int K1, int ld1,
    const float* __restrict__ X2, int ld2,
    const unsigned short* __restrict__ Bhi, const unsigned short* __restrict__ Blo,
    const float* __restrict__ cvec, const float* __restrict__ dis,
    void* __restrict__ outp, int ldC, int Dout, int K, int N)
{
    __shared__ float Xs[128 * 32];     // [row][k], 128B/row, XOR-swizzled 16B chunks
    const int tid = threadIdx.x;
    const int w = tid >> 6, lane = tid & 63;
    const int lr = lane & 15, lg = lane >> 4;
    const int brow = blockIdx.x * 128;
    const int nkc = (K + 31) >> 5;

    f32x4 acc[2][NCB];
#pragma unroll
    for (int cb = 0; cb < NCB; ++cb) {
        float cv = cvec[cb * 16 + lr];
        f32x4 iv = {cv, cv, cv, cv};
        acc[0][cb] = iv;
        acc[1][cb] = iv;
    }

    for (int kc = 0; kc < nkc; ++kc) {
        const int k0 = kc * 32;
#pragma unroll
        for (int p = 0; p < 4; ++p) {
            int fidx = (p * 256 + tid) * 4;
            int r = fidx >> 5;
            int c = fidx & 31;
            int grow = brow + r;
            int k = k0 + c;
            float4 val = make_float4(0.f, 0.f, 0.f, 0.f);
            if (grow < N) {
                if (k < K1)      val = *(const float4*)(X1 + (size_t)grow * ld1 + k);
                else if (k < K)  val = *(const float4*)(X2 + (size_t)grow * ld2 + (k - K1));
            }
            *(float4*)((char*)Xs + r * 128 + ((c * 4) ^ ((r & 7) << 4))) = val;
        }
        __syncthreads();

        bf16x8 ahi[2], alo[2];
#pragma unroll
        for (int rb = 0; rb < 2; ++rb) {
            int r = w * 32 + rb * 16 + lr;
            const char* base = (const char*)Xs + r * 128;
            int swz = (r & 7) << 4;
            int cb0 = lg * 32;
            float4 v0 = *(const float4*)(base + (cb0 ^ swz));
            float4 v1 = *(const float4*)(base + ((cb0 + 16) ^ swz));
            float xv[8] = {v0.x, v0.y, v0.z, v0.w, v1.x, v1.y, v1.z, v1.w};
#pragma unroll
            for (int i = 0; i < 8; ++i) {
                unsigned short h = f2bf(xv[i]);
                ahi[rb][i] = (short)h;
                alo[rb][i] = (short)f2bf(xv[i] - bf2f(h));
            }
        }

        const bf16x8* bh = (const bf16x8*)Bhi + (size_t)kc * NCB * 64;
        const bf16x8* bl = (const bf16x8*)Blo + (size_t)kc * NCB * 64;
#pragma unroll
        for (int cb = 0; cb < NCB; ++cb) {
            bf16x8 bhf = bh[cb * 64 + lane];
            bf16x8 blf = bl[cb * 64 + lane];
#pragma unroll
            for (int rb = 0; rb < 2; ++rb) {
                acc[rb][cb] = __builtin_amdgcn_mfma_f32_16x16x32_bf16(ahi[rb], bhf, acc[rb][cb], 0, 0, 0);
                acc[rb][cb] = __builtin_amdgcn_mfma_f32_16x16x32_bf16(ahi[rb], blf, acc[rb][cb], 0, 0, 0);
                acc[rb][cb] = __builtin_amdgcn_mfma_f32_16x16x32_bf16(alo[rb], bhf, acc[rb][cb], 0, 0, 0);
            }
        }
        __syncthreads();
    }

    // D lane map: row = (lane>>4)*4 + reg, col = lane&15
#pragma unroll
    for (int rb = 0; rb < 2; ++rb) {
#pragma unroll
        for (int r = 0; r < 4; ++r) {
            int grow = brow + w * 32 + rb * 16 + lg * 4 + r;
            if (grow >= N) continue;
            float d = dis[grow];
            if (BF16OUT) {
                unsigned short* hb = (unsigned short*)outp;
#pragma unroll
                for (int cb = 0; cb < NCB; ++cb) {
                    int col = cb * 16 + lr;
                    hb[(size_t)grow * 128 + col] = f2bf(d * acc[rb][cb][r]);
                }
            } else {
                float* fo = (float*)outp;
#pragma unroll
                for (int cb = 0; cb < NCB; ++cb) {
                    int col = cb * 16 + lr;
                    if (col < Dout) fo[(size_t)grow * ldC + col] = d * acc[rb][cb][r];
                }
            }
        }
    }
}

// ---------------------------------------------------------------------------
// 128-wide aggregation over bf16 rows (256B each): lanes split in two halves,
// each half fetches its own row stream (uint2 = 4 bf16 per lane), fp32 accum.
template <bool RELU>
__global__ __launch_bounds__(256) void agg128b_kernel(
    const unsigned short* __restrict__ hwb,
    const int* __restrict__ row_ptr, const int* __restrict__ csr,
    const float* __restrict__ dis, const float* __restrict__ bias,
    float* __restrict__ outp, int N)
{
    int wid = threadIdx.x >> 6, lane = threadIdx.x & 63;
    int node = blockIdx.x * 4 + wid;
    if (node >= N) return;
    const int half = lane >> 5, q = lane & 31;
    const uint2* hw2 = (const uint2*)hwb;      // 32 uint2 per 128-col row
    float a[4] = {0.f, 0.f, 0.f, 0.f};
    float b4[4] = {0.f, 0.f, 0.f, 0.f};
    if (half == 0) addbf(a, hw2[(size_t)node * 32 + q]);   // self loop
    int beg = row_ptr[node], end = row_ptr[node + 1];
    for (int base = beg; base < end; base += 64) {
        int idx = base + lane;
        int j = (idx < end) ? csr[idx] : 0;
        int cnt = end - base; if (cnt > 64) cnt = 64;
        int fullp = cnt >> 1;
        int t = 0;
        for (; t + 4 <= fullp; t += 4) {
            int ja = __shfl(j, 2 * t     + half);
            int jb = __shfl(j, 2 * t + 2 + half);
            int jc = __shfl(j, 2 * t + 4 + half);
            int jd = __shfl(j, 2 * t + 6 + half);
            uint2 va = hw2[(size_t)ja * 32 + q];
            uint2 vb = hw2[(size_t)jb * 32 + q];
            uint2 vc = hw2[(size_t)jc * 32 + q];
            uint2 vd = hw2[(size_t)jd * 32 + q];
            addbf(a, va); addbf(b4, vb); addbf(a, vc); addbf(b4, vd);
        }
        for (; t < fullp; ++t) {
            int ja = __shfl(j, 2 * t + half);
            uint2 va = hw2[(size_t)ja * 32 + q];
            addbf(a, va);
        }
        if (cnt & 1) {
            int ja = __shfl(j, cnt - 1);
            if (half == 0) { uint2 va = hw2[(size_t)ja * 32 + q]; addbf(a, va); }
        }
    }
#pragma unroll
    for (int c = 0; c < 4; ++c) {
        a[c] += b4[c];
        a[c] += __shfl_xor(a[c], 32);
    }
    if (half == 0) {
        float d = dis[node];
        float4 bv = ((const float4*)bias)[q];
        float4 o;
        o.x = fmaf(d, a[0], bv.x);
        o.y = fmaf(d, a[1], bv.y);
        o.z = fmaf(d, a[2], bv.z);
        o.w = fmaf(d, a[3], bv.w);
        if (RELU) {
            o.x = fmaxf(o.x, 0.f); o.y = fmaxf(o.y, 0.f);
            o.z = fmaxf(o.z, 0.f); o.w = fmaxf(o.w, 0.f);
        }
        ((float4*)outp)[(size_t)node * 32 + q] = o;
    }
}

// 40-wide aggregation over fp32 rows, 4-deep unroll.
__global__ __launch_bounds__(256) void agg40_kernel(
    const float* __restrict__ hw,
    const int* __restrict__ row_ptr, const int* __restrict__ csr,
    const float* __restrict__ dis, const float* __restrict__ bias,
    float* __restrict__ outp, int N)
{
    int wid = threadIdx.x >> 6, lane = threadIdx.x & 63;
    int node = blockIdx.x * 4 + wid;
    if (node >= N) return;
    bool act = lane < 40;
    float a0 = 0.f, a1 = 0.f, a2 = 0.f, a3 = 0.f;
    if (act) a0 = hw[(size_t)node * 40 + lane];
    int beg = row_ptr[node], end = row_ptr[node + 1];
    for (int base = beg; base < end; base += 64) {
        int idx = base + lane;
        int j = (idx < end) ? csr[idx] : 0;
        int cnt = end - base; if (cnt > 64) cnt = 64;
        int t = 0;
        for (; t + 4 <= cnt; t += 4) {
            int j0 = __shfl(j, t), j1 = __shfl(j, t + 1);
            int j2 = __shfl(j, t + 2), j3 = __shfl(j, t + 3);
            if (act) {
                a0 += hw[(size_t)j0 * 40 + lane];
                a1 += hw[(size_t)j1 * 40 + lane];
                a2 += hw[(size_t)j2 * 40 + lane];
                a3 += hw[(size_t)j3 * 40 + lane];
            }
        }
        for (; t < cnt; ++t) {
            int j0 = __shfl(j, t);
            if (act) a0 += hw[(size_t)j0 * 40 + lane];
        }
    }
    if (act) {
        float s = (a0 + a1) + (a2 + a3);
        outp[(size_t)node * 40 + lane] = fmaf(dis[node], s, bias[lane]);
    }
}

// ---------------------------------------------------------------------------
extern "C" void kernel_launch(void* const* d_in, const int* in_sizes, int n_in,
                              void* d_out, int out_size, void* d_ws, size_t ws_size,
                              hipStream_t stream) {
    const int N = in_sizes[0] / 100;
    const int E = in_sizes[1] / 2;

    const float* x   = (const float*)d_in[0];
    const void*  ei  = d_in[1];
    const float* W1  = (const float*)d_in[4];
    const float* b1  = (const float*)d_in[5];
    const float* W2  = (const float*)d_in[6];
    const float* b2  = (const float*)d_in[7];
    const float* Wm  = (const float*)d_in[8];
    const float* bm  = (const float*)d_in[9];
    const float* Wo  = (const float*)d_in[10];
    const float* bo  = (const float*)d_in[11];
    const float* bn1g = (const float*)d_in[12];
    const float* bn1b = (const float*)d_in[13];
    const float* bn1m = (const float*)d_in[14];
    const float* bn1v = (const float*)d_in[15];
    const float* bn2g = (const float*)d_in[16];
    const float* bn2b = (const float*)d_in[17];
    const float* bn2m = (const float*)d_in[18];
    const float* bn2v = (const float*)d_in[19];
    const float* bnmg = (const float*)d_in[20];
    const float* bnmb = (const float*)d_in[21];
    const float* bnmm = (const float*)d_in[22];
    const float* bnmv = (const float*)d_in[23];
    const float* bnog = (const float*)d_in[24];
    const float* bnob = (const float*)d_in[25];
    const float* bnom = (const float*)d_in[26];
    const float* bnov = (const float*)d_in[27];

    char* wsb = (char*)d_ws;
    size_t off = 0;
    auto alloc = [&](size_t elems) -> void* { void* p = wsb + off; off += elems * 4; return p; };
    int*   deg     = (int*)alloc(N);
    int*   cursor  = (int*)alloc(N);
    int*   row_ptr = (int*)alloc((size_t)N + 1);
    int*   bsum    = (int*)alloc(64);
    int*   flag    = (int*)alloc(1);
    off = (off + 15) & ~(size_t)15;
    float* dis  = (float*)alloc(N);
    int*   csr  = (int*)alloc(E);
    off = (off + 15) & ~(size_t)15;
    float* hw   = (float*)alloc((size_t)N * 128);   // fp32 arena; bf16 view reuses it
    unsigned short* hwb = (unsigned short*)hw;
    unsigned short* BhiA = (unsigned short*)alloc(63488);   // 126976 bf16 arena
    unsigned short* BloA = (unsigned short*)alloc(63488);
    float* cvecA = (float*)alloc(128 * 5);
    (void)ws_size; (void)n_in; (void)out_size;

    float* outF = (float*)d_out;
    float* h1 = outF + (size_t)N * 40;
    float* h2 = h1 + (size_t)N * 128;
    float* h3 = h2 + (size_t)N * 128;
    float* h4 = h3 + (size_t)N * 128;

    dim3 b256(256);

    // ---- fold all 5 layers' weights up front (independent of graph build)
    const int Boff[5]  = {0, 16384, 49152, 81920, 114688};
    struct FoldP { const float *W, *g, *b, *m, *v; int K, Dout, ncb; };
    FoldP fp[5] = {
        {W1, bn1g, bn1b, bn1m, bn1v, 100, 128, 8},
        {W2, bn2g, bn2b, bn2m, bn2v, 228, 128, 8},
        {Wm, bnmg, bnmb, bnmm, bnmv, 256, 128, 8},
        {Wm + 256 * 128, bnmg + 256, bnmb + 256, bnmm + 256, bnmv + 256, 256, 128, 8},
        {Wo, bnog, bnob, bnom, bnov, 256, 40, 3},
    };
    for (int l = 0; l < 5; ++l) {
        int nkc = (fp[l].K + 31) / 32;
        int ftotal = nkc * fp[l].ncb * 512;
        fold_b_kernel<<<dim3((ftotal + 255) / 256), b256, 0, stream>>>(
            fp[l].W, fp[l].g, fp[l].v, BhiA + Boff[l], BloA + Boff[l], fp[l].K, fp[l].Dout, fp[l].ncb);
        fold_c2_kernel<<<dim3(32), b256, 0, stream>>>(
            fp[l].W, fp[l].g, fp[l].b, fp[l].m, fp[l].v, cvecA + 128 * l, fp[l].K, fp[l].Dout);
    }

    // ---- graph build
    detect_kernel<<<1, 1024, 0, stream>>>((const int*)ei, flag);
    init_kernel<<<dim3((N + 255) / 256), b256, 0, stream>>>(deg, cursor, N);
    count_kernel<<<dim3((E + 255) / 256), b256, 0, stream>>>(ei, E, deg, flag);
    dis_kernel<<<dim3((N + 255) / 256), b256, 0, stream>>>(deg, dis, N);
    int nb = (N + 1023) / 1024;
    scanA_kernel<<<dim3(nb), dim3(1024), 0, stream>>>(deg, row_ptr, bsum, N);
    scanB_kernel<<<1, 64, 0, stream>>>(bsum, nb);
    scanC_kernel<<<dim3(nb), dim3(1024), 0, stream>>>(row_ptr, bsum, N);
    fill_kernel<<<dim3((E + 255) / 256), b256, 0, stream>>>(ei, E, row_ptr, cursor, csr, flag);

    int gemm_grid = (N + 127) / 128;
    int agg_grid  = (N + 3) / 4;

    auto layer = [&](int l, const float* X1, int K1, int ld1, const float* X2, int ld2,
                     const float* lb, int Dout, float* dst, bool relu) {
        int K = fp[l].K;
        const unsigned short* Bhi = BhiA + Boff[l];
        const unsigned short* Blo = BloA + Boff[l];
        const float* cv = cvecA + 128 * l;
        if (Dout == 128) {
            gemm_mfma_kernel<8, true><<<dim3(gemm_grid), b256, 0, stream>>>(
                X1, K1, ld1, X2, ld2, Bhi, Blo, cv, dis, hwb, 128, Dout, K, N);
            if (relu)
                agg128b_kernel<true><<<dim3(agg_grid), b256, 0, stream>>>(hwb, row_ptr, csr, dis, lb, dst, N);
            else
                agg128b_kernel<false><<<dim3(agg_grid), b256, 0, stream>>>(hwb, row_ptr, csr, dis, lb, dst, N);
        } else {
            gemm_mfma_kernel<3, false><<<dim3(gemm_grid), b256, 0, stream>>>(
                X1, K1, ld1, X2, ld2, Bhi, Blo, cv, dis, hw, 40, Dout, K, N);
            agg40_kernel<<<dim3(agg_grid), b256, 0, stream>>>(hw, row_ptr, csr, dis, lb, dst, N);
        }
    };

    // L1: bn1 + GCN(W1) + relu -> h1
    layer(0, x, 100, 100, nullptr, 0, b1, 128, h1, true);
    // L2: concat(h1, x) -> bn2 + GCN(W2) + relu -> h2
    layer(1, h1, 128, 128, x, 100, b2, 128, h2, true);
    // L3: concat(h2, h1) -> bnm[0] + GCN(Wm[0]) + relu -> h3
    layer(2, h2, 128, 128, h1, 128, bm, 128, h3, true);
    // L4: concat(h3, h2) -> bnm[1] + GCN(Wm[1]) + relu -> h4
    layer(3, h3, 128, 128, h2, 128, bm + 128, 128, h4, true);
    // L5: concat(h4, h3) -> bno + GCN(Wo) -> out (no relu)
    layer(4, h4, 128, 128, h3, 128, bo, 40, outF, false);
}